// Round 6
// baseline (211.401 us; speedup 1.0000x reference)
//
#include <hip/hip_runtime.h>
#include <hip/hip_bf16.h>

typedef __bf16 bf16;
typedef bf16 bf16x8 __attribute__((ext_vector_type(8)));
typedef bf16 bf16x4 __attribute__((ext_vector_type(4)));
typedef float f32x4 __attribute__((ext_vector_type(4)));

#define BAR()   asm volatile("s_barrier" ::: "memory")
#define LGKM0() asm volatile("s_waitcnt lgkmcnt(0)" ::: "memory")

__device__ __forceinline__ void gload_lds16(const void* g, void* l) {
    __builtin_amdgcn_global_load_lds(
        (const __attribute__((address_space(1))) void*)g,
        (__attribute__((address_space(3))) void*)l, 16, 0, 0);
}

// ---------------------------------------------------------------------------
// 128x256 NT-GEMM core, BK=32, 8 waves (2M x 4N, per-wave 64x64), 48KB
// double-buffered LDS -> 2 blocks/CU (16 waves/CU).  r4-proven schedule:
// stage tile t+1 (3 gloads), vmcnt(3) [t landed, t+1 in flight], BAR,
// 8x ds_read_b128 (conflict-free via chunk XOR), 16 MFMA, lgkm0, BAR.
// Swizzle (4 chunks/row, 64B rows): LDS chunk c holds global chunk
// c ^ ((row>>1)&3); applied on the global source (linear gload_lds dest)
// and re-applied on ds_read addresses (both-sides rule).
// Buffer layout: A[128][32] @0 (8KB), B[256][32] @8KB (16KB); bufs at 0/24KB.
// ---------------------------------------------------------------------------
__device__ __forceinline__
void gemm_core_bk32(const bf16* __restrict__ Ag, const bf16* __restrict__ Bg,
                    const int ldA, const int ldB, const int NT,
                    char* smem, f32x4 (&acc)[4][4])
{
    const int t    = threadIdx.x;          // 0..511
    const int lane = t & 63;
    const int wid  = t >> 6;               // 0..7
    const int wrow = wid >> 2;             // 0..1  (M half)
    const int wcol = wid & 3;              // 0..3  (N quarter)
    const int rl   = lane & 15;
    const int hi   = lane >> 4;
    const int ko   = ((hi ^ ((rl >> 1) & 3)) << 4);   // swizzled chunk offset

    // staging map: thread t -> row t>>2 (0..127), chunk t&3;
    // source chunk = (t&3) ^ ((row>>1)&3) = (t&3) ^ ((t>>3)&3)
    const int arow = t >> 2;
    const int sch  = (t & 3) ^ ((t >> 3) & 3);
    const bf16* pA  = Ag + (long long)arow * ldA + sch * 8;
    const bf16* pB0 = Bg + (long long)arow * ldB + sch * 8;
    const bf16* pB1 = pB0 + 128ll * ldB;
    char* uw = smem + (t & ~63) * 16;      // wave-uniform dest (+HW lane*16)

#define STG32(tt) { char* db = uw + ((tt) & 1) * 24576; const int kk = (tt) * 32; \
    gload_lds16(pA  + kk, db); \
    gload_lds16(pB0 + kk, db + 8192); \
    gload_lds16(pB1 + kk, db + 16384); }

    STG32(0);
    for (int tt = 0; tt < NT; ++tt) {
        if (tt + 1 < NT) {
            STG32(tt + 1);
            asm volatile("s_waitcnt vmcnt(3)" ::: "memory");   // tile tt landed
        } else {
            asm volatile("s_waitcnt vmcnt(0)" ::: "memory");
        }
        BAR();
        const char* aB = smem + (tt & 1) * 24576;
        const char* bB = aB + 8192;
        bf16x8 af[4], bfr[4];
#pragma unroll
        for (int m = 0; m < 4; ++m)
            af[m]  = *(const bf16x8*)(aB + (wrow * 64 + m * 16 + rl) * 64 + ko);
#pragma unroll
        for (int n = 0; n < 4; ++n)
            bfr[n] = *(const bf16x8*)(bB + (wcol * 64 + n * 16 + rl) * 64 + ko);
        __builtin_amdgcn_s_setprio(1);
#pragma unroll
        for (int m = 0; m < 4; ++m)
#pragma unroll
            for (int n = 0; n < 4; ++n)
                acc[m][n] = __builtin_amdgcn_mfma_f32_16x16x32_bf16(
                                af[m], bfr[n], acc[m][n], 0, 0, 0);
        __builtin_amdgcn_s_setprio(0);
        LGKM0();      // reads of buf[tt&1] done before next iter's staging
        BAR();
    }
#undef STG32
}

// ---------------------------------------------------------------------------
// Merged QKV projections, 128x256 tiles: grid (12, 64), XCD-remapped so each
// XCD owns 8 contiguous A-panels (2MB, L2-resident).  bx = mat*4 + nc.
// ---------------------------------------------------------------------------
__global__ __launch_bounds__(512, 4)
void gemm_qkv(const bf16* __restrict__ Xq, const bf16* __restrict__ Xk,
              const bf16* __restrict__ Xv,
              const bf16* __restrict__ Wt3,
              float* __restrict__ outQ, bf16* __restrict__ Qb,
              bf16* __restrict__ Kb, bf16* __restrict__ Vt)
{
    extern __shared__ char smem[];
    // bijective XCD remap: dispatch id -> (xcd, chunk) -> tile T
    const int id0 = blockIdx.x + 12 * blockIdx.y;
    const int T   = (id0 & 7) * 96 + (id0 >> 3);
    const int bxn = T % 12, byn = T / 12;          // bxn 0..11, byn 0..63
    const int mat = bxn >> 2, nc = bxn & 3;

    const bf16* A = (mat == 0 ? Xq : mat == 1 ? Xk : Xv) + (long long)byn * 128 * 1024;
    const bf16* B = Wt3 + (long long)mat * 1024 * 1024 + (long long)nc * 256 * 1024;
    f32x4 acc[4][4] = {};
    gemm_core_bk32(A, B, 1024, 1024, 32, smem, acc);

    const int t = threadIdx.x, lane = t & 63, wid = t >> 6;
    const int wr = (wid >> 2) * 64, wc = (wid & 3) * 64;
    const int rl = lane & 15, rg4 = (lane >> 4) * 4;
#pragma unroll
    for (int m = 0; m < 4; ++m)
#pragma unroll
        for (int n = 0; n < 4; ++n)
#pragma unroll
            for (int j = 0; j < 4; ++j) {
                const int row = byn * 128 + wr + m * 16 + rg4 + j;
                const int col = nc * 256 + wc + n * 16 + rl;
                const float v = acc[m][n][j];
                if (mat == 0) { outQ[(long long)row * 1024 + col] = v;
                                Qb[(long long)row * 1024 + col] = (bf16)v; }
                else if (mat == 1) Kb[(long long)row * 1024 + col] = (bf16)v;
                else Vt[(long long)col * 8192 + row] = (bf16)v;
            }
}

// ---------------------------------------------------------------------------
// QK^T causal, 128x256 tiles: grid (8, 16, 4); skip fully-masked tiles
// (2*bx > by); diagonal-crossing tiles computed full (softmax masks).
// ---------------------------------------------------------------------------
__global__ __launch_bounds__(512, 4)
void gemm_sc(const bf16* __restrict__ Qb, const bf16* __restrict__ Kb,
             float* __restrict__ scores, float scale)
{
    if (2 * blockIdx.x > blockIdx.y) return;
    extern __shared__ char smem[];
    const int bx = blockIdx.x, by = blockIdx.y, bz = blockIdx.z;
    const long long boff = (long long)bz * 2048 * 1024;
    f32x4 acc[4][4] = {};
    gemm_core_bk32(Qb + boff + (long long)by * 128 * 1024,
                   Kb + boff + (long long)bx * 256 * 1024, 1024, 1024, 32, smem, acc);

    const int t = threadIdx.x, lane = t & 63, wid = t >> 6;
    const int wr = (wid >> 2) * 64, wc = (wid & 3) * 64;
    const int rl = lane & 15, rg4 = (lane >> 4) * 4;
    float* Cb = scores + (long long)bz * 2048 * 2048;
#pragma unroll
    for (int m = 0; m < 4; ++m)
#pragma unroll
        for (int n = 0; n < 4; ++n)
#pragma unroll
            for (int j = 0; j < 4; ++j) {
                const int row = by * 128 + wr + m * 16 + rg4 + j;
                const int col = bx * 256 + wc + n * 16 + rl;
                Cb[(long long)row * 2048 + col] = acc[m][n][j] * scale;
            }
}

// ---------------------------------------------------------------------------
// Round-4 128x128 core (verified): BK=64, 64KB double-buffer, vmcnt(8),
// XOR chunk swizzle.  Used for PV (K-limited, load-balanced dispatch).
// ---------------------------------------------------------------------------
__device__ __forceinline__
void gemm_core128(const bf16* __restrict__ A0, const bf16* __restrict__ B0,
                  const int ldA, const int ldB, const int NT,
                  char* smem, f32x4 (&acc)[4][4])
{
    const int t    = threadIdx.x;
    const int lane = t & 63;
    const int wid  = t >> 6;
    const int wr   = (wid >> 1) * 64;
    const int wc   = (wid & 1) * 64;
    const int rl   = lane & 15;
    const int hi   = lane >> 4;
    const int r7   = lane & 7;

    const int tr = t >> 3;
    const int gc = (t & 7) ^ (tr & 7);
    const bf16* pA = A0 + (long long)tr * ldA + gc * 8;
    const bf16* pB = B0 + (long long)tr * ldB + gc * 8;
    char* stBase = smem + (t & ~63) * 16;

#define STAGE128(tt) { \
    char* db = stBase + ((tt) & 1) * 32768; \
    const bf16* a_ = pA + (tt) * 64; \
    const bf16* b_ = pB + (tt) * 64; \
    gload_lds16(a_,              db); \
    gload_lds16(a_ + 32ll * ldA, db + 4096); \
    gload_lds16(a_ + 64ll * ldA, db + 8192); \
    gload_lds16(a_ + 96ll * ldA, db + 12288); \
    gload_lds16(b_,              db + 16384); \
    gload_lds16(b_ + 32ll * ldB, db + 20480); \
    gload_lds16(b_ + 64ll * ldB, db + 24576); \
    gload_lds16(b_ + 96ll * ldB, db + 28672); }

    STAGE128(0);
    for (int tt = 0; tt < NT; ++tt) {
        if (tt + 1 < NT) {
            STAGE128(tt + 1);
            asm volatile("s_waitcnt vmcnt(8)" ::: "memory");
        } else {
            asm volatile("s_waitcnt vmcnt(0)" ::: "memory");
        }
        BAR();
        const char* ba = smem + (tt & 1) * 32768;
        const char* bb = ba + 16384;
#pragma unroll
        for (int ks = 0; ks < 2; ++ks) {
            bf16x8 af[4], bfr[4];
#pragma unroll
            for (int m = 0; m < 4; ++m) {
                const int r = wr + m * 16 + rl;
                af[m] = *(const bf16x8*)(ba + r * 128 + ((((ks << 2) | hi) ^ r7) << 4));
            }
#pragma unroll
            for (int n = 0; n < 4; ++n) {
                const int r = wc + n * 16 + rl;
                bfr[n] = *(const bf16x8*)(bb + r * 128 + ((((ks << 2) | hi) ^ r7) << 4));
            }
            __builtin_amdgcn_s_setprio(1);
#pragma unroll
            for (int m = 0; m < 4; ++m)
#pragma unroll
                for (int n = 0; n < 4; ++n)
                    acc[m][n] = __builtin_amdgcn_mfma_f32_16x16x32_bf16(
                                    af[m], bfr[n], acc[m][n], 0, 0, 0);
            __builtin_amdgcn_s_setprio(0);
        }
        LGKM0();
        BAR();
    }
#undef STAGE128
}

// ---------------------------------------------------------------------------
// PV: 1D grid 512 -> (bz, bx, by) with by interleaved heavy/light for load
// balance.  A = P (bf16, ld 4096), B = Vt (ld 8192), NT = (by+1)*2.
// ---------------------------------------------------------------------------
__global__ __launch_bounds__(256, 2)
void gemm_pv(const bf16* __restrict__ P, const bf16* __restrict__ Vt,
             float* __restrict__ outA)
{
    extern __shared__ char smem[];
    int F = blockIdx.x;
    const int bz = F & 3;
    const int bx = (F >> 2) & 7;
    const int byr = F >> 5;                       // 0..15
    const int by = (byr & 1) ? (byr >> 1) : (15 - (byr >> 1));
    f32x4 acc[4][4] = {};
    gemm_core128(P + (long long)bz * 2048 * 4096 + (long long)by * 128 * 4096,
                 Vt + (long long)bx * 128 * 8192 + (long long)bz * 2048,
                 4096, 8192, (by + 1) * 2, smem, acc);

    const int t = threadIdx.x, lane = t & 63, wid = t >> 6;
    const int wr = (wid >> 1) * 64, wc = (wid & 1) * 64;
    const int rl = lane & 15, rg4 = (lane >> 4) * 4;
    float* Cb = outA + (long long)bz * 2048 * 1024;
#pragma unroll
    for (int m = 0; m < 4; ++m)
#pragma unroll
        for (int n = 0; n < 4; ++n)
#pragma unroll
            for (int j = 0; j < 4; ++j) {
                const int row = by * 128 + wr + m * 16 + rg4 + j;
                const int col = bx * 128 + wc + n * 16 + rl;
                Cb[(long long)row * 1024 + col] = acc[m][n][j];
            }
}

// ---------------------------------------------------------------------------
// f32 -> bf16 convert for the three X inputs.
// ---------------------------------------------------------------------------
__global__ __launch_bounds__(256)
void convert_x(const float* __restrict__ X0, const float* __restrict__ X1,
               const float* __restrict__ X2,
               bf16* __restrict__ Y0, bf16* __restrict__ Y1, bf16* __restrict__ Y2)
{
    const int which = blockIdx.x >> 12;
    const long long base = (((long long)(blockIdx.x & 4095)) * 256 + threadIdx.x) * 8;
    const float* X = which == 0 ? X0 : which == 1 ? X1 : X2;
    bf16*       Y = which == 0 ? Y0 : which == 1 ? Y1 : Y2;
    float4 a = *(const float4*)(X + base);
    float4 b = *(const float4*)(X + base + 4);
    bf16x8 v;
    v[0] = (bf16)a.x; v[1] = (bf16)a.y; v[2] = (bf16)a.z; v[3] = (bf16)a.w;
    v[4] = (bf16)b.x; v[5] = (bf16)b.y; v[6] = (bf16)b.z; v[7] = (bf16)b.w;
    *(bf16x8*)(Y + base) = v;
}

// ---------------------------------------------------------------------------
// Transpose-convert all three W into contiguous Wt3[mat][n][k]: grid (32,32,3).
// ---------------------------------------------------------------------------
__global__ __launch_bounds__(256)
void transpose_w3(const float* __restrict__ W0, const float* __restrict__ W1,
                  const float* __restrict__ W2, bf16* __restrict__ Wt3)
{
    __shared__ float tile[32][33];
    const int w = blockIdx.z;
    const float* W = w == 0 ? W0 : w == 1 ? W1 : W2;
    bf16* Wt = Wt3 + (size_t)w * 1024 * 1024;
    const int bx = blockIdx.x * 32;
    const int by = blockIdx.y * 32;
    const int tx = threadIdx.x;
    const int ty = threadIdx.y;
    for (int i = ty; i < 32; i += 8)
        tile[i][tx] = W[(size_t)(by + i) * 1024 + bx + tx];
    __syncthreads();
    for (int i = ty; i < 32; i += 8)
        Wt[(size_t)(bx + i) * 1024 + by + tx] = (bf16)tile[tx][i];
}

// ---------------------------------------------------------------------------
// Causal row softmax, in place f32 -> bf16 (zero-fill to 256-boundary).
// ---------------------------------------------------------------------------
__global__ __launch_bounds__(256)
void softmax_causal(float* __restrict__ scores)
{
    __shared__ float buf[2048];
    __shared__ float red[8];
    const int row = blockIdx.x;           // b*2048 + q
    const int q   = row & 2047;
    float* srow = scores + (size_t)row * 2048;
    bf16*  prow = (bf16*)srow;
    const int L = q + 1;
    const int tileEnd = ((q >> 8) + 1) << 8;
    const int t = threadIdx.x;
    const int lane = t & 63, wv = t >> 6;

    float m = -INFINITY;
    for (int k = t * 4; k < tileEnd; k += 1024) {
        float4 v = *(const float4*)(srow + k);
        float4 w;
        w.x = (k + 0 < L) ? v.x : -INFINITY;
        w.y = (k + 1 < L) ? v.y : -INFINITY;
        w.z = (k + 2 < L) ? v.z : -INFINITY;
        w.w = (k + 3 < L) ? v.w : -INFINITY;
        *(float4*)(buf + k) = w;
        m = fmaxf(fmaxf(fmaxf(m, w.x), w.y), fmaxf(w.z, w.w));
    }
#pragma unroll
    for (int o = 32; o; o >>= 1) m = fmaxf(m, __shfl_xor(m, o));
    if (lane == 0) red[wv] = m;
    __syncthreads();
    m = fmaxf(fmaxf(red[0], red[1]), fmaxf(red[2], red[3]));

    float s = 0.f;
    for (int k = t * 4; k < tileEnd; k += 1024) {
        float4 v = *(float4*)(buf + k);
        float4 e;
        e.x = __expf(v.x - m); e.y = __expf(v.y - m);
        e.z = __expf(v.z - m); e.w = __expf(v.w - m);
        s += (e.x + e.y) + (e.z + e.w);
        *(float4*)(buf + k) = e;
    }
#pragma unroll
    for (int o = 32; o; o >>= 1) s += __shfl_xor(s, o);
    if (lane == 0) red[4 + wv] = s;
    __syncthreads();
    s = (red[4] + red[5]) + (red[6] + red[7]);
    const float inv = 1.f / s;

    for (int k = t * 4; k < tileEnd; k += 1024) {
        float4 v = *(float4*)(buf + k);
        bf16x4 o;
        o[0] = (bf16)(v.x * inv); o[1] = (bf16)(v.y * inv);
        o[2] = (bf16)(v.z * inv); o[3] = (bf16)(v.w * inv);
        *(bf16x4*)(prow + k) = o;
    }
}

// ---------------------------------------------------------------------------
// Launch
// ---------------------------------------------------------------------------
extern "C" void kernel_launch(void* const* d_in, const int* in_sizes, int n_in,
                              void* d_out, int out_size, void* d_ws, size_t ws_size,
                              hipStream_t stream)
{
    const float* Xk = (const float*)d_in[0];
    const float* Xv = (const float*)d_in[1];
    const float* Xq = (const float*)d_in[2];
    const float* WK = (const float*)d_in[3];
    const float* WV = (const float*)d_in[4];
    const float* WQ = (const float*)d_in[5];

    float* outQ = (float*)d_out;                       // [4,2048,1024] f32
    float* outA = outQ + (size_t)8192 * 1024;          // [4,2048,1024] f32

    char* ws = (char*)d_ws;
    bf16*  Qb     = (bf16*)(ws);                       // 16MB
    bf16*  Kb     = (bf16*)(ws + (16ull << 20));       // 16MB
    bf16*  Vt     = (bf16*)(ws + (32ull << 20));       // 16MB  [1024][8192]
    float* scores = (float*)(ws + (48ull << 20));      // 64MB  [4][2048][2048]
    bf16*  Xqb    = (bf16*)(ws + (48ull << 20));       // aliases scores
    bf16*  Xkb    = Xqb + (size_t)8 * 1024 * 1024;
    bf16*  Xvb    = Xkb + (size_t)8 * 1024 * 1024;
    bf16*  Wt3    = Xvb + (size_t)8 * 1024 * 1024;     // [3][1024][1024] bf16
    const float scale = 0.022097086912079608f;         // 1/sqrt(2048)

    hipFuncSetAttribute((const void*)gemm_qkv, hipFuncAttributeMaxDynamicSharedMemorySize, 49152);
    hipFuncSetAttribute((const void*)gemm_sc,  hipFuncAttributeMaxDynamicSharedMemorySize, 49152);
    hipFuncSetAttribute((const void*)gemm_pv,  hipFuncAttributeMaxDynamicSharedMemorySize, 65536);

    convert_x<<<dim3(12288), 256, 0, stream>>>(Xq, Xk, Xv, Xqb, Xkb, Xvb);

    transpose_w3<<<dim3(32, 32, 3), dim3(32, 8), 0, stream>>>(WQ, WK, WV, Wt3);

    gemm_qkv<<<dim3(12, 64), 512, 49152, stream>>>(
        Xqb, Xkb, Xvb, Wt3, outQ, Qb, Kb, Vt);

    gemm_sc<<<dim3(8, 16, 4), 512, 49152, stream>>>(Qb, Kb, scores, scale);

    softmax_causal<<<dim3(8192), 256, 0, stream>>>(scores);

    gemm_pv<<<dim3(512), 256, 65536, stream>>>((const bf16*)scores, Vt, outA);
}

// Round 8
// 191.498 us; speedup vs baseline: 1.1039x; 1.1039x over previous
//
#include <hip/hip_runtime.h>
#include <hip/hip_bf16.h>

typedef __bf16 bf16;
typedef bf16 bf16x8 __attribute__((ext_vector_type(8)));
typedef bf16 bf16x4 __attribute__((ext_vector_type(4)));
typedef float f32x4 __attribute__((ext_vector_type(4)));

#define BAR()   asm volatile("s_barrier" ::: "memory")
#define LGKM0() asm volatile("s_waitcnt lgkmcnt(0)" ::: "memory")

__device__ __forceinline__ void gload_lds16(const void* g, void* l) {
    __builtin_amdgcn_global_load_lds(
        (const __attribute__((address_space(1))) void*)g,
        (__attribute__((address_space(3))) void*)l, 16, 0, 0);
}

// ---------------------------------------------------------------------------
// 128x256 NT-GEMM core, BK=32, 8 waves (2M x 4N, per-wave 64x64), 48KB
// double-buffered LDS.  Verified r6 schedule: stage tile t+1 (3 gloads),
// vmcnt(3), BAR, 8x ds_read_b128 (conflict-free via chunk XOR), 16 MFMA,
// lgkm0, BAR.  Swizzle: LDS chunk c holds global chunk c ^ ((row>>1)&3);
// applied on the global source (linear gload_lds dest) and on ds_reads.
// Buffer layout: A[128][32] @0 (8KB), B[256][32] @8KB (16KB); bufs at 0/24KB.
// ---------------------------------------------------------------------------
__device__ __forceinline__
void gemm_core_bk32(const bf16* __restrict__ Ag, const bf16* __restrict__ Bg,
                    const int ldA, const int ldB, const int NT,
                    char* smem, f32x4 (&acc)[4][4])
{
    const int t    = threadIdx.x;          // 0..511
    const int lane = t & 63;
    const int wid  = t >> 6;               // 0..7
    const int wrow = wid >> 2;             // 0..1  (M half)
    const int wcol = wid & 3;              // 0..3  (N quarter)
    const int rl   = lane & 15;
    const int hi   = lane >> 4;
    const int ko   = ((hi ^ ((rl >> 1) & 3)) << 4);   // swizzled chunk offset

    const int arow = t >> 2;
    const int sch  = (t & 3) ^ ((t >> 3) & 3);
    const bf16* pA  = Ag + (long long)arow * ldA + sch * 8;
    const bf16* pB0 = Bg + (long long)arow * ldB + sch * 8;
    const bf16* pB1 = pB0 + 128ll * ldB;
    char* uw = smem + (t & ~63) * 16;      // wave-uniform dest (+HW lane*16)

#define STG32(tt) { char* db = uw + ((tt) & 1) * 24576; const int kk = (tt) * 32; \
    gload_lds16(pA  + kk, db); \
    gload_lds16(pB0 + kk, db + 8192); \
    gload_lds16(pB1 + kk, db + 16384); }

    STG32(0);
    for (int tt = 0; tt < NT; ++tt) {
        if (tt + 1 < NT) {
            STG32(tt + 1);
            asm volatile("s_waitcnt vmcnt(3)" ::: "memory");   // tile tt landed
        } else {
            asm volatile("s_waitcnt vmcnt(0)" ::: "memory");
        }
        BAR();
        const char* aB = smem + (tt & 1) * 24576;
        const char* bB = aB + 8192;
        bf16x8 af[4], bfr[4];
#pragma unroll
        for (int m = 0; m < 4; ++m)
            af[m]  = *(const bf16x8*)(aB + (wrow * 64 + m * 16 + rl) * 64 + ko);
#pragma unroll
        for (int n = 0; n < 4; ++n)
            bfr[n] = *(const bf16x8*)(bB + (wcol * 64 + n * 16 + rl) * 64 + ko);
        __builtin_amdgcn_s_setprio(1);
#pragma unroll
        for (int m = 0; m < 4; ++m)
#pragma unroll
            for (int n = 0; n < 4; ++n)
                acc[m][n] = __builtin_amdgcn_mfma_f32_16x16x32_bf16(
                                af[m], bfr[n], acc[m][n], 0, 0, 0);
        __builtin_amdgcn_s_setprio(0);
        LGKM0();
        BAR();
    }
#undef STG32
}

// ---------------------------------------------------------------------------
// Merged QKV projections, 128x256 tiles: grid (12, 64), XCD-remapped.
// mat==2 (V) epilogue: LDS-staged transpose -> coalesced Vt writes.
// ---------------------------------------------------------------------------
__global__ __launch_bounds__(512, 4)
void gemm_qkv(const bf16* __restrict__ Xq, const bf16* __restrict__ Xk,
              const bf16* __restrict__ Xv,
              const bf16* __restrict__ Wt3,
              float* __restrict__ outQ, bf16* __restrict__ Qb,
              bf16* __restrict__ Kb, bf16* __restrict__ Vt)
{
    extern __shared__ char smem[];
    const int id0 = blockIdx.x + 12 * blockIdx.y;
    const int T   = (id0 & 7) * 96 + (id0 >> 3);
    const int bxn = T % 12, byn = T / 12;
    const int mat = bxn >> 2, nc = bxn & 3;

    const bf16* A = (mat == 0 ? Xq : mat == 1 ? Xk : Xv) + (long long)byn * 128 * 1024;
    const bf16* B = Wt3 + (long long)mat * 1024 * 1024 + (long long)nc * 256 * 1024;
    f32x4 acc[4][4] = {};
    gemm_core_bk32(A, B, 1024, 1024, 32, smem, acc);

    const int t = threadIdx.x, lane = t & 63, wid = t >> 6;
    const int wr = (wid >> 2) * 64, wc = (wid & 3) * 64;
    const int rl = lane & 15, rg4 = (lane >> 4) * 4;

    if (mat != 2) {
#pragma unroll
        for (int m = 0; m < 4; ++m)
#pragma unroll
            for (int n = 0; n < 4; ++n)
#pragma unroll
                for (int j = 0; j < 4; ++j) {
                    const int row = byn * 128 + wr + m * 16 + rg4 + j;
                    const int col = nc * 256 + wc + n * 16 + rl;
                    const float v = acc[m][n][j];
                    if (mat == 0) { outQ[(long long)row * 1024 + col] = v;
                                    Qb[(long long)row * 1024 + col] = (bf16)v; }
                    else Kb[(long long)row * 1024 + col] = (bf16)v;
                }
    } else {
        // V: transpose via LDS (two 128-col halves; swizzled [128][128] bf16)
        char* lT = smem;                      // 32KB of the 48KB
#pragma unroll
        for (int h = 0; h < 2; ++h) {
            BAR();
            if ((wc >> 7) == h) {             // this wave's cols in this half
#pragma unroll
                for (int m = 0; m < 4; ++m)
#pragma unroll
                    for (int n = 0; n < 4; ++n) {
                        const int cp = (wc & 127) + n * 16 + rl;      // 0..127
                        const int rb = wr + m * 16 + rg4;             // 0..124
                        bf16x4 v;
                        v[0] = (bf16)acc[m][n][0]; v[1] = (bf16)acc[m][n][1];
                        v[2] = (bf16)acc[m][n][2]; v[3] = (bf16)acc[m][n][3];
                        *(bf16x4*)(lT + cp * 256 + ((rb * 2) ^ ((cp & 7) << 4))) = v;
                    }
            }
            BAR();
            // read-out: col c2 = t>>2, 4 passes over the 16 chunks of the row
            const int c2 = t >> 2;
#pragma unroll
            for (int it = 0; it < 4; ++it) {
                const int q = (t & 3) + it * 4;                      // 0..15
                bf16x8 v = *(const bf16x8*)(lT + c2 * 256 + ((q << 4) ^ ((c2 & 7) << 4)));
                *(bf16x8*)(Vt + (long long)(nc * 256 + h * 128 + c2) * 8192
                              + byn * 128 + q * 8) = v;
            }
        }
    }
}

// ---------------------------------------------------------------------------
// QK^T causal, 128x256 tiles: grid (8, 16, 4); skip fully-masked tiles.
// ---------------------------------------------------------------------------
__global__ __launch_bounds__(512, 4)
void gemm_sc(const bf16* __restrict__ Qb, const bf16* __restrict__ Kb,
             float* __restrict__ scores, float scale)
{
    if (2 * blockIdx.x > blockIdx.y) return;
    extern __shared__ char smem[];
    const int bx = blockIdx.x, by = blockIdx.y, bz = blockIdx.z;
    const long long boff = (long long)bz * 2048 * 1024;
    f32x4 acc[4][4] = {};
    gemm_core_bk32(Qb + boff + (long long)by * 128 * 1024,
                   Kb + boff + (long long)bx * 256 * 1024, 1024, 1024, 32, smem, acc);

    const int t = threadIdx.x, lane = t & 63, wid = t >> 6;
    const int wr = (wid >> 2) * 64, wc = (wid & 3) * 64;
    const int rl = lane & 15, rg4 = (lane >> 4) * 4;
    float* Cb = scores + (long long)bz * 2048 * 2048;
#pragma unroll
    for (int m = 0; m < 4; ++m)
#pragma unroll
        for (int n = 0; n < 4; ++n)
#pragma unroll
            for (int j = 0; j < 4; ++j) {
                const int row = by * 128 + wr + m * 16 + rg4 + j;
                const int col = bx * 256 + wc + n * 16 + rl;
                Cb[(long long)row * 2048 + col] = acc[m][n][j] * scale;
            }
}

// ---------------------------------------------------------------------------
// PV: 128x256 tiles, grid 256 -> (bz, bx 0..3, by 0..15 interleaved).
// A = P (bf16, ld 4096), B = Vt (ld 8192), NT = (by+1)*4 (K-limit).
// ---------------------------------------------------------------------------
__global__ __launch_bounds__(512, 4)
void gemm_pv(const bf16* __restrict__ P, const bf16* __restrict__ Vt,
             float* __restrict__ outA)
{
    extern __shared__ char smem[];
    const int F = blockIdx.x;
    const int bz = F & 3;
    const int bx = (F >> 2) & 3;
    const int byr = F >> 4;                       // 0..15
    const int by = (byr & 1) ? (byr >> 1) : (15 - (byr >> 1));
    f32x4 acc[4][4] = {};
    gemm_core_bk32(P + (long long)bz * 2048 * 4096 + (long long)by * 128 * 4096,
                   Vt + (long long)bx * 256 * 8192 + (long long)bz * 2048,
                   4096, 8192, (by + 1) * 4, smem, acc);

    const int t = threadIdx.x, lane = t & 63, wid = t >> 6;
    const int wr = (wid >> 2) * 64, wc = (wid & 3) * 64;
    const int rl = lane & 15, rg4 = (lane >> 4) * 4;
    float* Cb = outA + (long long)bz * 2048 * 1024;
#pragma unroll
    for (int m = 0; m < 4; ++m)
#pragma unroll
        for (int n = 0; n < 4; ++n)
#pragma unroll
            for (int j = 0; j < 4; ++j) {
                const int row = by * 128 + wr + m * 16 + rg4 + j;
                const int col = bx * 256 + wc + n * 16 + rl;
                Cb[(long long)row * 1024 + col] = acc[m][n][j];
            }
}

// ---------------------------------------------------------------------------
// f32 -> bf16 convert for the three X inputs.
// ---------------------------------------------------------------------------
__global__ __launch_bounds__(256)
void convert_x(const float* __restrict__ X0, const float* __restrict__ X1,
               const float* __restrict__ X2,
               bf16* __restrict__ Y0, bf16* __restrict__ Y1, bf16* __restrict__ Y2)
{
    const int which = blockIdx.x >> 12;
    const long long base = (((long long)(blockIdx.x & 4095)) * 256 + threadIdx.x) * 8;
    const float* X = which == 0 ? X0 : which == 1 ? X1 : X2;
    bf16*       Y = which == 0 ? Y0 : which == 1 ? Y1 : Y2;
    float4 a = *(const float4*)(X + base);
    float4 b = *(const float4*)(X + base + 4);
    bf16x8 v;
    v[0] = (bf16)a.x; v[1] = (bf16)a.y; v[2] = (bf16)a.z; v[3] = (bf16)a.w;
    v[4] = (bf16)b.x; v[5] = (bf16)b.y; v[6] = (bf16)b.z; v[7] = (bf16)b.w;
    *(bf16x8*)(Y + base) = v;
}

// ---------------------------------------------------------------------------
// Transpose-convert all three W into contiguous Wt3[mat][n][k]: grid (32,32,3).
// ---------------------------------------------------------------------------
__global__ __launch_bounds__(256)
void transpose_w3(const float* __restrict__ W0, const float* __restrict__ W1,
                  const float* __restrict__ W2, bf16* __restrict__ Wt3)
{
    __shared__ float tile[32][33];
    const int w = blockIdx.z;
    const float* W = w == 0 ? W0 : w == 1 ? W1 : W2;
    bf16* Wt = Wt3 + (size_t)w * 1024 * 1024;
    const int bx = blockIdx.x * 32;
    const int by = blockIdx.y * 32;
    const int tx = threadIdx.x;
    const int ty = threadIdx.y;
    for (int i = ty; i < 32; i += 8)
        tile[i][tx] = W[(size_t)(by + i) * 1024 + bx + tx];
    __syncthreads();
    for (int i = ty; i < 32; i += 8)
        Wt[(size_t)(bx + i) * 1024 + by + tx] = (bf16)tile[tx][i];
}

// ---------------------------------------------------------------------------
// Causal row softmax, in place f32 -> bf16 (zero-fill to 256-boundary).
// ---------------------------------------------------------------------------
__global__ __launch_bounds__(256)
void softmax_causal(float* __restrict__ scores)
{
    __shared__ float buf[2048];
    __shared__ float red[8];
    const int row = blockIdx.x;           // b*2048 + q
    const int q   = row & 2047;
    float* srow = scores + (size_t)row * 2048;
    bf16*  prow = (bf16*)srow;
    const int L = q + 1;
    const int tileEnd = ((q >> 8) + 1) << 8;
    const int t = threadIdx.x;
    const int lane = t & 63, wv = t >> 6;

    float m = -INFINITY;
    for (int k = t * 4; k < tileEnd; k += 1024) {
        float4 v = *(const float4*)(srow + k);
        float4 w;
        w.x = (k + 0 < L) ? v.x : -INFINITY;
        w.y = (k + 1 < L) ? v.y : -INFINITY;
        w.z = (k + 2 < L) ? v.z : -INFINITY;
        w.w = (k + 3 < L) ? v.w : -INFINITY;
        *(float4*)(buf + k) = w;
        m = fmaxf(fmaxf(fmaxf(m, w.x), w.y), fmaxf(w.z, w.w));
    }
#pragma unroll
    for (int o = 32; o; o >>= 1) m = fmaxf(m, __shfl_xor(m, o));
    if (lane == 0) red[wv] = m;
    __syncthreads();
    m = fmaxf(fmaxf(red[0], red[1]), fmaxf(red[2], red[3]));

    float s = 0.f;
    for (int k = t * 4; k < tileEnd; k += 1024) {
        float4 v = *(float4*)(buf + k);
        float4 e;
        e.x = __expf(v.x - m); e.y = __expf(v.y - m);
        e.z = __expf(v.z - m); e.w = __expf(v.w - m);
        s += (e.x + e.y) + (e.z + e.w);
        *(float4*)(buf + k) = e;
    }
#pragma unroll
    for (int o = 32; o; o >>= 1) s += __shfl_xor(s, o);
    if (lane == 0) red[4 + wv] = s;
    __syncthreads();
    s = (red[4] + red[5]) + (red[6] + red[7]);
    const float inv = 1.f / s;

    for (int k = t * 4; k < tileEnd; k += 1024) {
        float4 v = *(float4*)(buf + k);
        bf16x4 o;
        o[0] = (bf16)(v.x * inv); o[1] = (bf16)(v.y * inv);
        o[2] = (bf16)(v.z * inv); o[3] = (bf16)(v.w * inv);
        *(bf16x4*)(prow + k) = o;
    }
}

// ---------------------------------------------------------------------------
// Launch
// ---------------------------------------------------------------------------
extern "C" void kernel_launch(void* const* d_in, const int* in_sizes, int n_in,
                              void* d_out, int out_size, void* d_ws, size_t ws_size,
                              hipStream_t stream)
{
    const float* Xk = (const float*)d_in[0];
    const float* Xv = (const float*)d_in[1];
    const float* Xq = (const float*)d_in[2];
    const float* WK = (const float*)d_in[3];
    const float* WV = (const float*)d_in[4];
    const float* WQ = (const float*)d_in[5];

    float* outQ = (float*)d_out;                       // [4,2048,1024] f32
    float* outA = outQ + (size_t)8192 * 1024;          // [4,2048,1024] f32

    char* ws = (char*)d_ws;
    bf16*  Qb     = (bf16*)(ws);                       // 16MB
    bf16*  Kb     = (bf16*)(ws + (16ull << 20));       // 16MB
    bf16*  Vt     = (bf16*)(ws + (32ull << 20));       // 16MB  [1024][8192]
    float* scores = (float*)(ws + (48ull << 20));      // 64MB  [4][2048][2048]
    bf16*  Xqb    = (bf16*)(ws + (48ull << 20));       // aliases scores
    bf16*  Xkb    = Xqb + (size_t)8 * 1024 * 1024;
    bf16*  Xvb    = Xkb + (size_t)8 * 1024 * 1024;
    bf16*  Wt3    = Xvb + (size_t)8 * 1024 * 1024;     // [3][1024][1024] bf16
    const float scale = 0.022097086912079608f;         // 1/sqrt(2048)

    hipFuncSetAttribute((const void*)gemm_qkv, hipFuncAttributeMaxDynamicSharedMemorySize, 49152);
    hipFuncSetAttribute((const void*)gemm_sc,  hipFuncAttributeMaxDynamicSharedMemorySize, 49152);
    hipFuncSetAttribute((const void*)gemm_pv,  hipFuncAttributeMaxDynamicSharedMemorySize, 49152);

    convert_x<<<dim3(12288), 256, 0, stream>>>(Xq, Xk, Xv, Xqb, Xkb, Xvb);

    transpose_w3<<<dim3(32, 32, 3), dim3(32, 8), 0, stream>>>(WQ, WK, WV, Wt3);

    gemm_qkv<<<dim3(12, 64), 512, 49152, stream>>>(
        Xqb, Xkb, Xvb, Wt3, outQ, Qb, Kb, Vt);

    gemm_sc<<<dim3(8, 16, 4), 512, 49152, stream>>>(Qb, Kb, scores, scale);

    softmax_causal<<<dim3(8192), 256, 0, stream>>>(scores);

    gemm_pv<<<dim3(256), 512, 49152, stream>>>((const bf16*)scores, Vt, outA);
}